// Round 1
// baseline (203.111 us; speedup 1.0000x reference)
//
#include <hip/hip_runtime.h>
#include <math.h>

#define B_ 64
#define T_ 256
#define K_ 128

// Linear-domain (scaled) CRF forward. One block per batch element.
// Lane (it = tid>>3, jt = tid&7) owns E rows [it*4, it*4+4) x cols [jt*16, jt*16+16)
// in registers (E = exp(trans), loaded once). v lives in double-buffered, padded LDS.
__global__ __launch_bounds__(256) void crf_fwd_kernel(
    const float* __restrict__ y,
    const float* __restrict__ mask,
    const float* __restrict__ trans,
    float* __restrict__ out)
{
    const int b   = blockIdx.x;
    const int tid = threadIdx.x;
    const int it  = tid >> 3;      // 0..31 : row group (rows it*4 .. it*4+3)
    const int jt  = tid & 7;       // 0..7  : col group (cols jt*16 .. jt*16+15)
    const int i0  = it << 2;
    const int wv  = tid >> 6;      // wave 0..3

    // v layout: 8 groups of 16 floats, group stride 20 floats (80 B):
    //   value j stored at (j>>4)*20 + (j&15).
    // 80 B is 16B-aligned (b128 ok) and the 8 group bases hit distinct bank quads.
    __shared__ __align__(16) float vbuf[2][160];
    __shared__ float maskS[T_];
    __shared__ __align__(16) float partS[4];

    maskS[tid] = mask[b * T_ + tid];
    if (tid < K_)
        vbuf[0][((tid >> 4) * 20) + (tid & 15)] = (tid == 2) ? 1.0f : 0.0f; // one-hot SOS

    // E fragment: E[c][q] = exp(trans[i0+c][jt*16 + 4q .. +3])
    float4 E[4][4];
    #pragma unroll
    for (int c = 0; c < 4; ++c) {
        const float4* tp = (const float4*)(trans + (i0 + c) * K_ + (jt << 4));
        #pragma unroll
        for (int q = 0; q < 4; ++q) {
            float4 v = tp[q];
            E[c][q] = make_float4(__expf(v.x), __expf(v.y), __expf(v.z), __expf(v.w));
        }
    }

    const float* yb = y + (size_t)b * (T_ * K_);
    const int iy = i0 + (jt & 3);   // the i this lane owns after the butterfly
    const int b0 = jt & 1;
    const int b1 = (jt >> 1) & 1;

    float c_acc = 0.0f;   // log normalizer (block-uniform)
    int   cur   = 0;
    int   since = 0;

    __syncthreads();

    for (int t = 0; t < T_; ++t) {
        float mt = maskS[t];
        if (mt != 0.0f) {            // block-uniform branch; masked step = score unchanged
            float yv = yb[t * K_ + iy];                       // overlaps with LDS reads/FMAs
            const float4* vp = (const float4*)&vbuf[cur][jt * 20];
            float4 v0 = vp[0], v1 = vp[1], v2 = vp[2], v3 = vp[3];

            float p[4];
            #pragma unroll
            for (int c = 0; c < 4; ++c) {
                float s = E[c][0].x * v0.x;
                s = fmaf(E[c][0].y, v0.y, s);
                s = fmaf(E[c][0].z, v0.z, s);
                s = fmaf(E[c][0].w, v0.w, s);
                s = fmaf(E[c][1].x, v1.x, s);
                s = fmaf(E[c][1].y, v1.y, s);
                s = fmaf(E[c][1].z, v1.z, s);
                s = fmaf(E[c][1].w, v1.w, s);
                s = fmaf(E[c][2].x, v2.x, s);
                s = fmaf(E[c][2].y, v2.y, s);
                s = fmaf(E[c][2].z, v2.z, s);
                s = fmaf(E[c][2].w, v2.w, s);
                s = fmaf(E[c][3].x, v3.x, s);
                s = fmaf(E[c][3].y, v3.y, s);
                s = fmaf(E[c][3].z, v3.z, s);
                s = fmaf(E[c][3].w, v3.w, s);
                p[c] = s;
            }

            // Halving butterfly over the 8 jt-lanes (same it). Keep the half whose
            // i-bit matches the corresponding jt-bit => lane ends with u_{i0 + (jt&3)}.
            float sa = b0 ? p[0] : p[1];
            float sb = b0 ? p[2] : p[3];
            float ra = __shfl_xor(sa, 1);
            float rb = __shfl_xor(sb, 1);
            float q0 = (b0 ? p[1] : p[0]) + ra;   // i-bit0 = b0, bit1 = 0
            float q1 = (b0 ? p[3] : p[2]) + rb;   // i-bit0 = b0, bit1 = 1
            float scv = b1 ? q0 : q1;
            float rc  = __shfl_xor(scv, 2);
            float u   = (b1 ? q1 : q0) + rc;      // i = i0 + b0 + 2*b1
            u += __shfl_xor(u, 4);                // jt and jt^4 now identical (2x redundant)

            float w = __expf(yv) * u;

            if (++since == 4) {                   // renormalize every 4 active steps
                since = 0;
                float s = w;                      // 64-lane sum = 2 * sum over wave's 32 i's
                s += __shfl_xor(s, 1);
                s += __shfl_xor(s, 2);
                s += __shfl_xor(s, 4);
                s += __shfl_xor(s, 8);
                s += __shfl_xor(s, 16);
                s += __shfl_xor(s, 32);
                if ((tid & 63) == 0) partS[wv] = s * 0.5f;
                __syncthreads();
                float4 ps = *((const float4*)partS);
                float S = (ps.x + ps.y) + (ps.z + ps.w);
                c_acc += __logf(S);
                w *= 1.0f / S;
            }

            const int nxt = cur ^ 1;
            if ((jt & 4) == 0)                    // lanes jt<4 cover each i exactly once
                vbuf[nxt][((iy >> 4) * 20) + (iy & 15)] = w;
            __syncthreads();
            cur = nxt;
        }
    }

    // out[b] = c_acc + log(sum_i v_i)
    float v = 0.0f;
    if (tid < K_) v = vbuf[cur][((tid >> 4) * 20) + (tid & 15)];
    float s = v;
    s += __shfl_xor(s, 1);
    s += __shfl_xor(s, 2);
    s += __shfl_xor(s, 4);
    s += __shfl_xor(s, 8);
    s += __shfl_xor(s, 16);
    s += __shfl_xor(s, 32);
    if ((tid & 63) == 0) partS[wv] = s;   // waves 2,3 contribute 0
    __syncthreads();
    float4 ps = *((const float4*)partS);
    float S = (ps.x + ps.y) + (ps.z + ps.w);
    if (tid == 0) out[b] = c_acc + __logf(S);
}

extern "C" void kernel_launch(void* const* d_in, const int* in_sizes, int n_in,
                              void* d_out, int out_size, void* d_ws, size_t ws_size,
                              hipStream_t stream) {
    const float* y     = (const float*)d_in[0];   // (B, T, K) fp32
    const float* mask  = (const float*)d_in[1];   // (B, T)    fp32 0/1
    const float* trans = (const float*)d_in[2];   // (K, K)    fp32
    float* out = (float*)d_out;                    // (B,)      fp32
    crf_fwd_kernel<<<B_, 256, 0, stream>>>(y, mask, trans, out);
}

// Round 2
// 172.725 us; speedup vs baseline: 1.1759x; 1.1759x over previous
//
#include <hip/hip_runtime.h>
#include <math.h>

#define B_ 64
#define T_ 256
#define K_ 128

typedef const __attribute__((address_space(1))) void* gas1_t;
typedef __attribute__((address_space(3))) void* las3_t;

// Linear-domain (scaled) CRF forward. One block per batch element.
// Lane (it = tid>>3, jt = tid&7) owns E rows [it*4, it*4+4) x cols [jt*16, jt*16+16)
// in registers (E = exp(trans)). v double-buffered in padded LDS. y staged into
// LDS in 16KB chunks via global_load_lds so the scan loop never touches global
// memory (the vmcnt(0) drain at every __syncthreads was the R0 killer).
__global__ __launch_bounds__(256) void crf_fwd_kernel(
    const float* __restrict__ y,
    const float* __restrict__ mask,
    const float* __restrict__ trans,
    float* __restrict__ out)
{
    const int b    = blockIdx.x;
    const int tid  = threadIdx.x;
    const int lane = tid & 63;
    const int wv   = tid >> 6;     // wave 0..3
    const int it   = tid >> 3;     // 0..31 row group
    const int jt   = tid & 7;      // 0..7 col group
    const int i0   = it << 2;
    const int iy   = i0 + (jt & 3);
    const int b0   = jt & 1;
    const int b1   = (jt >> 1) & 1;

    __shared__ __align__(16) float ybufS[2][32 * K_];  // 2 x 16 KB chunk buffers
    __shared__ __align__(16) float vbuf[2][160];       // padded: j -> (j>>4)*20 + (j&15)
    __shared__ __align__(16) float partS[4];
    __shared__ int lenS[4];

    const float* yb = y + (size_t)b * (T_ * K_);

    // ---- async chunk staging: chunk c (32 steps) -> ybufS[buf] ----
    auto stage = [&](int c, int buf) {
        const float* gp = yb + (size_t)c * (32 * K_);
        #pragma unroll
        for (int q = 0; q < 4; ++q) {
            const int seg = (wv << 2) | q;   // 16 segments x 1 KB
            __builtin_amdgcn_global_load_lds(
                (gas1_t)(gp + seg * 256 + lane * 4),
                (las3_t)(&ybufS[buf][seg * 256]),
                16, 0, 0);
        }
    };

    stage(0, 0);
    stage(1, 1);

    // ---- sequence length (mask is contiguous: arange < length) ----
    float mv = mask[b * T_ + tid];
    unsigned long long ball = __ballot(mv != 0.0f);
    if (lane == 0) lenS[wv] = __popcll(ball);

    // ---- init v = one-hot SOS ----
    if (tid < K_)
        vbuf[0][((tid >> 4) * 20) + (tid & 15)] = (tid == 2) ? 1.0f : 0.0f;

    // ---- E fragment: E[c][q] = exp(trans[i0+c][jt*16 + 4q .. +3]) ----
    float4 E[4][4];
    #pragma unroll
    for (int c = 0; c < 4; ++c) {
        const float4* tp = (const float4*)(trans + (i0 + c) * K_ + (jt << 4));
        #pragma unroll
        for (int q = 0; q < 4; ++q) {
            float4 v = tp[q];
            E[c][q] = make_float4(__expf(v.x), __expf(v.y), __expf(v.z), __expf(v.w));
        }
    }

    __syncthreads();   // drains chunk 0/1 DMA + vbuf/lenS writes
    const int L = lenS[0] + lenS[1] + lenS[2] + lenS[3];

    float c_acc = 0.0f;
    int   cur   = 0;

    for (int t = 0; t < L; ++t) {
        const int cb = (t >> 5) & 1;
        const int tt = t & 31;

        const float4* vp = (const float4*)&vbuf[cur][jt * 20];
        float4 v0 = vp[0], v1 = vp[1], v2 = vp[2], v3 = vp[3];
        float yv = ybufS[cb][tt * K_ + iy];    // LDS broadcast read
        float ey = __expf(yv);                  // off the v-dependent path

        // 4 rows x 16-term dots, 2 accumulators each (8-deep chains)
        float p[4];
        #pragma unroll
        for (int c = 0; c < 4; ++c) {
            float s0 = E[c][0].x * v0.x;
            s0 = fmaf(E[c][0].y, v0.y, s0);
            s0 = fmaf(E[c][0].z, v0.z, s0);
            s0 = fmaf(E[c][0].w, v0.w, s0);
            s0 = fmaf(E[c][1].x, v1.x, s0);
            s0 = fmaf(E[c][1].y, v1.y, s0);
            s0 = fmaf(E[c][1].z, v1.z, s0);
            s0 = fmaf(E[c][1].w, v1.w, s0);
            float s1 = E[c][2].x * v2.x;
            s1 = fmaf(E[c][2].y, v2.y, s1);
            s1 = fmaf(E[c][2].z, v2.z, s1);
            s1 = fmaf(E[c][2].w, v2.w, s1);
            s1 = fmaf(E[c][3].x, v3.x, s1);
            s1 = fmaf(E[c][3].y, v3.y, s1);
            s1 = fmaf(E[c][3].z, v3.z, s1);
            s1 = fmaf(E[c][3].w, v3.w, s1);
            p[c] = s0 + s1;
        }

        // renorm every 4 active steps: S from the v we already loaded
        // (overlaps the FMA chain; no extra barrier)
        const bool rn = ((t & 3) == 3);
        float rinv = 1.0f, lS = 0.0f;
        if (rn) {
            float4 vs = make_float4(v0.x + v1.x + v2.x + v3.x,
                                    v0.y + v1.y + v2.y + v3.y,
                                    v0.z + v1.z + v2.z + v3.z,
                                    v0.w + v1.w + v2.w + v3.w);
            float sl = (vs.x + vs.y) + (vs.z + vs.w);
            sl += __shfl_xor(sl, 1);
            sl += __shfl_xor(sl, 2);
            sl += __shfl_xor(sl, 4);   // uniform: Σ_j v_j
            rinv = 1.0f / sl;
            lS = __logf(sl);
        }

        // halving butterfly over the 8 jt-lanes: 3 dependent shuffle levels
        float ra = __shfl_xor(b0 ? p[0] : p[1], 1);
        float rb = __shfl_xor(b0 ? p[2] : p[3], 1);
        float q0 = (b0 ? p[1] : p[0]) + ra;
        float q1 = (b0 ? p[3] : p[2]) + rb;
        float rc = __shfl_xor(b1 ? q0 : q1, 2);
        float u  = (b1 ? q1 : q0) + rc;
        u += __shfl_xor(u, 4);          // i = i0 + b0 + 2*b1, 2x redundant in jt^4

        float w = ey * u;
        if (rn) { w *= rinv; c_acc += lS; }

        const int nxt = cur ^ 1;
        if ((jt & 4) == 0)
            vbuf[nxt][((iy >> 4) * 20) + (iy & 15)] = w;
        __syncthreads();
        cur = nxt;

        if (tt == 31) {                 // chunk (t>>5) fully consumed; refill its buffer
            const int c2 = (t >> 5) + 2;
            if (c2 < 8) stage(c2, cb);
        }
    }

    // out[b] = c_acc + log(sum_i v_i)
    float v = 0.0f;
    if (tid < K_) v = vbuf[cur][((tid >> 4) * 20) + (tid & 15)];
    float s = v;
    s += __shfl_xor(s, 1);
    s += __shfl_xor(s, 2);
    s += __shfl_xor(s, 4);
    s += __shfl_xor(s, 8);
    s += __shfl_xor(s, 16);
    s += __shfl_xor(s, 32);
    if (lane == 0) partS[wv] = s;       // waves 2,3 contribute 0
    __syncthreads();
    float4 ps = *((const float4*)partS);
    float S = (ps.x + ps.y) + (ps.z + ps.w);
    if (tid == 0) out[b] = c_acc + __logf(S);
}

extern "C" void kernel_launch(void* const* d_in, const int* in_sizes, int n_in,
                              void* d_out, int out_size, void* d_ws, size_t ws_size,
                              hipStream_t stream) {
    const float* y     = (const float*)d_in[0];   // (B, T, K) fp32
    const float* mask  = (const float*)d_in[1];   // (B, T)    fp32 0/1
    const float* trans = (const float*)d_in[2];   // (K, K)    fp32
    float* out = (float*)d_out;                    // (B,)      fp32
    crf_fwd_kernel<<<B_, 256, 0, stream>>>(y, mask, trans, out);
}